// Round 1
// baseline (2750.067 us; speedup 1.0000x reference)
//
#include <hip/hip_runtime.h>

using f32x4  = __attribute__((ext_vector_type(4))) float;
using short8 = __attribute__((ext_vector_type(8))) short;
using u32x4  = __attribute__((ext_vector_type(4))) unsigned int;

#define DEV __device__ __forceinline__
#define MFMA16(a, b, c) __builtin_amdgcn_mfma_f32_16x16x32_bf16(a, b, c, 0, 0, 0)

// B=32, CIN=1, NBINS=128, NFRAMES=256, NFILT=64 -> Hc=64, Wc=128
// context: [2048][8192] (row m = b*64+l, col f = c*128+w)
// DDEC=512, G=1536, T=64, NCLS=17

DEV unsigned short f2bf(float f) {
  unsigned int u = __float_as_uint(f);
  unsigned int r = (u + 0x7fffu + ((u >> 16) & 1u)) >> 16;
  return (unsigned short)r;
}
DEV float bf2f(unsigned short s) { return __uint_as_float(((unsigned int)s) << 16); }
DEV float sigm(float x) { return 1.0f / (1.0f + expf(-x)); }

// ---------------- K1: prep (split weights to bf16 hi/lo, zero state, init out) ----
__global__ __launch_bounds__(256) void k_prep(
    const float* __restrict__ wih, const float* __restrict__ whh,
    const float* __restrict__ outb,
    unsigned short* __restrict__ wih_hi, unsigned short* __restrict__ wih_lo,
    unsigned short* __restrict__ whh_hi, unsigned short* __restrict__ whh_lo,
    unsigned int* __restrict__ hbuf, float* __restrict__ kdot,
    float* __restrict__ bdot, int* __restrict__ syncb,
    float* __restrict__ d_out) {
  unsigned int i = blockIdx.x * 256u + threadIdx.x;
  if (i < 12582912u) {
    float w = wih[i];
    unsigned short h = f2bf(w);
    wih_hi[i] = h;
    wih_lo[i] = f2bf(w - bf2f(h));
  }
  if (i < 786432u) {
    float w = whh[i];
    unsigned short h = f2bf(w);
    whh_hi[i] = h;
    whh_lo[i] = f2bf(w - bf2f(h));
  }
  if (i < 32768u) hbuf[i] = 0u;
  if (i < 2080u) { kdot[i] = 0.f; bdot[i] = 0.f; }
  if (i < 2u) syncb[i] = 0;
  if (i < 34816u) d_out[i] = outb[i % 17u];  // out init = bias
}

// ---------------- K2: conv 3x3 stride2 pad1 -> context (bf16 hi/lo) --------------
__global__ __launch_bounds__(128) void k_conv(
    const float* __restrict__ x, const float* __restrict__ cw,
    unsigned short* __restrict__ ctx_hi, unsigned short* __restrict__ ctx_lo) {
  __shared__ float w[576];
  int t = threadIdx.x;
  for (int i = t; i < 576; i += 128) w[i] = cw[i];
  int blk = blockIdx.x;  // b*64 + h
  int b = blk >> 6, h = blk & 63;
  const float* xb = x + (size_t)b * 32768;  // 128*256
  int wcol = t;
  float xv[3][3];
  int ih0 = 2 * h - 1, iw0 = 2 * wcol - 1;
#pragma unroll
  for (int kh = 0; kh < 3; kh++) {
    int ih = ih0 + kh;
#pragma unroll
    for (int kw = 0; kw < 3; kw++) {
      int iw = iw0 + kw;
      bool ok = (ih >= 0) && (ih < 128) && (iw >= 0) && (iw < 256);
      xv[kh][kw] = ok ? xb[ih * 256 + iw] : 0.f;
    }
  }
  __syncthreads();
  size_t base = (size_t)blk * 8192 + wcol;
  for (int c = 0; c < 64; c++) {
    const float* wc = &w[c * 9];
    float acc = 0.f;
#pragma unroll
    for (int kh = 0; kh < 3; kh++)
#pragma unroll
      for (int kw = 0; kw < 3; kw++) acc += xv[kh][kw] * wc[kh * 3 + kw];
    unsigned short hi = f2bf(acc);
    ctx_hi[base + c * 128] = hi;
    ctx_lo[base + c * 128] = f2bf(acc - bf2f(hi));
  }
}

// ---------------- K3: ctxW = context @ W_ih^T  (split-bf16, 3-term MFMA) ---------
// A: [2048][8192] (hi/lo), B: [1536][8192] (hi/lo), C stored as ctxW[l][b][n]
__global__ __launch_bounds__(256) void k_gemm(
    const unsigned short* __restrict__ A_hi, const unsigned short* __restrict__ A_lo,
    const unsigned short* __restrict__ B_hi, const unsigned short* __restrict__ B_lo,
    float* __restrict__ ctxW) {
  __shared__ unsigned short Ah[128 * 32], Al[128 * 32], Bh[128 * 32], Bl[128 * 32];
  int tid = threadIdx.x;
  int m0 = blockIdx.x * 128, n0 = blockIdx.y * 128;
  int wave = tid >> 6, lane = tid & 63;
  int wm = wave >> 1, wn = wave & 1;
  const f32x4 zero4 = {0.f, 0.f, 0.f, 0.f};
  f32x4 acc[4][4];
  for (int mi = 0; mi < 4; mi++)
    for (int ni = 0; ni < 4; ni++) acc[mi][ni] = zero4;

  for (int k0 = 0; k0 < 8192; k0 += 32) {
    __syncthreads();
#pragma unroll
    for (int i = 0; i < 2; i++) {
      int c = tid + i * 256;            // 0..511 chunks of 8 bf16
      int row = c >> 2, col = (c & 3) << 3;
      size_t ga = (size_t)(m0 + row) * 8192 + k0 + col;
      size_t gb = (size_t)(n0 + row) * 8192 + k0 + col;
      *(short8*)&Ah[row * 32 + col] = *(const short8*)&A_hi[ga];
      *(short8*)&Al[row * 32 + col] = *(const short8*)&A_lo[ga];
      *(short8*)&Bh[row * 32 + col] = *(const short8*)&B_hi[gb];
      *(short8*)&Bl[row * 32 + col] = *(const short8*)&B_lo[gb];
    }
    __syncthreads();
    int kc = (lane >> 4) * 8;
    short8 ah[4], al[4], bh[4], bl[4];
#pragma unroll
    for (int mi = 0; mi < 4; mi++) {
      int r = wm * 64 + mi * 16 + (lane & 15);
      ah[mi] = *(short8*)&Ah[r * 32 + kc];
      al[mi] = *(short8*)&Al[r * 32 + kc];
    }
#pragma unroll
    for (int ni = 0; ni < 4; ni++) {
      int r = wn * 64 + ni * 16 + (lane & 15);
      bh[ni] = *(short8*)&Bh[r * 32 + kc];
      bl[ni] = *(short8*)&Bl[r * 32 + kc];
    }
#pragma unroll
    for (int mi = 0; mi < 4; mi++)
#pragma unroll
      for (int ni = 0; ni < 4; ni++) {
        acc[mi][ni] = MFMA16(ah[mi], bh[ni], acc[mi][ni]);
        acc[mi][ni] = MFMA16(ah[mi], bl[ni], acc[mi][ni]);
        acc[mi][ni] = MFMA16(al[mi], bh[ni], acc[mi][ni]);
      }
  }
#pragma unroll
  for (int mi = 0; mi < 4; mi++)
#pragma unroll
    for (int ni = 0; ni < 4; ni++) {
      int n = n0 + wn * 64 + ni * 16 + (lane & 15);
#pragma unroll
      for (int r = 0; r < 4; r++) {
        int m = m0 + wm * 64 + mi * 16 + (lane >> 4) * 4 + r;
        // ctxW[l][b][n], m = b*64 + l
        ctxW[(size_t)((m & 63) * 32 + (m >> 6)) * 1536 + n] = acc[mi][ni][r];
      }
    }
}

// ---------------- K4: sequential scan, 32 wgs (16 j-lanes each), 1 grid sync/step
#define NWG 32

DEV void grid_sync(int* ctr, int* gen, int nwg) {
  __syncthreads();
  if (threadIdx.x == 0) {
    int g = __hip_atomic_load(gen, __ATOMIC_RELAXED, __HIP_MEMORY_SCOPE_AGENT);
    int prev = __hip_atomic_fetch_add(ctr, 1, __ATOMIC_ACQ_REL, __HIP_MEMORY_SCOPE_AGENT);
    if (prev == nwg - 1) {
      __hip_atomic_store(ctr, 0, __ATOMIC_RELAXED, __HIP_MEMORY_SCOPE_AGENT);
      __hip_atomic_fetch_add(gen, 1, __ATOMIC_RELEASE, __HIP_MEMORY_SCOPE_AGENT);
    } else {
      while (__hip_atomic_load(gen, __ATOMIC_ACQUIRE, __HIP_MEMORY_SCOPE_AGENT) == g)
        __builtin_amdgcn_s_sleep(8);
    }
  }
  __syncthreads();
}

__global__ __launch_bounds__(512) void k_scan(
    const float* __restrict__ ctxW,
    const unsigned short* __restrict__ whh_hi, const unsigned short* __restrict__ whh_lo,
    const float* __restrict__ kw, const float* __restrict__ bw,
    const float* __restrict__ ow,
    unsigned int* __restrict__ hbuf, float* __restrict__ kdot, float* __restrict__ bdot,
    int* __restrict__ syncb, float* __restrict__ d_out) {
  __shared__ float ws_lds[32][64];   // attention weights
  __shared__ float gh_lds[32][48];   // gh for this j-slice (r|z|n blocks of 16)
  __shared__ float h_old[32][16];    // this wg's f32 hidden slice
  __shared__ float kappa_l[32], beta_l[32];

  const int g = blockIdx.x;          // j-slice id
  const int tid = threadIdx.x;
  const int b = tid >> 4, jj = tid & 15;
  const int wave = tid >> 6, lane = tid & 63;
  const int j0 = g * 16;
  const f32x4 zero4 = {0.f, 0.f, 0.f, 0.f};

  h_old[b][jj] = 0.f;
  if (tid < 32) kappa_l[tid] = 0.f;
  __syncthreads();

  for (int t = 0; t < 64; t++) {
    // P0: kappa/beta scalars for step t (deltas from h_t were added at step t-1)
    if (tid < 32) {
      kappa_l[tid] += __hip_atomic_load(&kdot[t * 32 + tid], __ATOMIC_RELAXED,
                                        __HIP_MEMORY_SCOPE_AGENT);
      beta_l[tid] = expf(__hip_atomic_load(&bdot[t * 32 + tid], __ATOMIC_RELAXED,
                                           __HIP_MEMORY_SCOPE_AGENT));
    }
    __syncthreads();
    // P1: attention weights (all 32x64), wg0 writes the ws output
    for (int i = tid; i < 2048; i += 512) {
      int bb = i >> 6, l = i & 63;
      float d = kappa_l[bb] - (float)l;
      float wv = expf(-beta_l[bb] * d * d);
      ws_lds[bb][l] = wv;
      if (g == 0) d_out[34816 + ((bb << 6) + t) * 64 + l] = wv;
    }
    __syncthreads();
    // P2: gx for this thread's (b, j) triple (r,z,n)
    float gx0 = 0.f, gx1 = 0.f, gx2 = 0.f;
    {
      const float* cbase = ctxW + (size_t)b * 1536 + j0 + jj;
#pragma unroll 4
      for (int l = 0; l < 64; l++) {
        float wv = ws_lds[b][l];
        const float* cp = cbase + (size_t)l * (32 * 1536);
        gx0 += wv * cp[0];
        gx1 += wv * cp[512];
        gx2 += wv * cp[1024];
      }
    }
    // P3: gh = h_t @ W_hh_slice^T via split-bf16 MFMA (waves 0..5)
    if (wave < 6) {
      int mt = wave & 1, nt = wave >> 1;
      int arow = mt * 16 + (lane & 15);          // batch index
      int ncol = nt * 16 + (lane & 15);
      int n_g = nt * 512 + j0 + (lane & 15);     // global gate-row
      const unsigned int* hsrc = hbuf + (t & 1) * 16384 + (size_t)arow * 512;
      f32x4 acc = zero4;
      for (int ks = 0; ks < 16; ks++) {
        int kc = ks * 32 + (lane >> 4) * 8;
        unsigned int au[8];
#pragma unroll
        for (int q = 0; q < 8; q++)
          au[q] = __hip_atomic_load(&hsrc[kc + q], __ATOMIC_RELAXED,
                                    __HIP_MEMORY_SCOPE_AGENT);
        short8 ah, al;
#pragma unroll
        for (int q = 0; q < 8; q++) {
          ah[q] = (short)(au[q] >> 16);
          al[q] = (short)(au[q] & 0xffffu);
        }
        short8 bh = *(const short8*)&whh_hi[(size_t)n_g * 512 + kc];
        short8 bl = *(const short8*)&whh_lo[(size_t)n_g * 512 + kc];
        acc = MFMA16(ah, bh, acc);
        acc = MFMA16(ah, bl, acc);
        acc = MFMA16(al, bh, acc);
      }
#pragma unroll
      for (int r = 0; r < 4; r++)
        gh_lds[mt * 16 + (lane >> 4) * 4 + r][ncol] = acc[r];
    }
    __syncthreads();
    // P4: gates + hidden update (thread owns (b, jj))
    float rr = sigm(gx0 + gh_lds[b][jj]);
    float zz = sigm(gx1 + gh_lds[b][16 + jj]);
    float nn = tanhf(gx2 + rr * gh_lds[b][32 + jj]);
    float h = (1.f - zz) * nn + zz * h_old[b][jj];
    h_old[b][jj] = h;
    unsigned short hh = f2bf(h);
    unsigned short hl = f2bf(h - bf2f(hh));
    __hip_atomic_store(&hbuf[((t + 1) & 1) * 16384 + b * 512 + j0 + jj],
                       ((unsigned int)hh << 16) | (unsigned int)hl,
                       __ATOMIC_RELAXED, __HIP_MEMORY_SCOPE_AGENT);
    // partial dots for next step's kappa/beta
    float kd = h * kw[j0 + jj];
    float bd = h * bw[j0 + jj];
#pragma unroll
    for (int m = 1; m < 16; m <<= 1) {
      kd += __shfl_xor(kd, m, 64);
      bd += __shfl_xor(bd, m, 64);
    }
    if (jj == 0) {
      atomicAdd(&kdot[(t + 1) * 32 + b], kd);
      atomicAdd(&bdot[(t + 1) * 32 + b], bd);
    }
    __syncthreads();
    // P5: partial out projection (onto bias-initialized d_out)
    for (int i = tid; i < 544; i += 512) {
      int bo = i / 17, k = i - bo * 17;
      const float* owr = ow + k * 512 + j0;
      float s = 0.f;
#pragma unroll
      for (int j = 0; j < 16; j++) s += h_old[bo][j] * owr[j];
      atomicAdd(&d_out[((bo << 6) + t) * 17 + k], s);
    }
    grid_sync(syncb, syncb + 1, NWG);
  }
}

// ---------------- launch ----------------
extern "C" void kernel_launch(void* const* d_in, const int* in_sizes, int n_in,
                              void* d_out, int out_size, void* d_ws, size_t ws_size,
                              hipStream_t stream) {
  (void)in_sizes; (void)n_in; (void)out_size; (void)ws_size;
  const float* x   = (const float*)d_in[0];
  const float* cw  = (const float*)d_in[2];
  const float* kw  = (const float*)d_in[3];
  const float* bw  = (const float*)d_in[4];
  const float* wih = (const float*)d_in[5];
  const float* whh = (const float*)d_in[6];
  const float* ow  = (const float*)d_in[7];
  const float* ob  = (const float*)d_in[8];
  float* out = (float*)d_out;
  char* ws = (char*)d_ws;

  unsigned short* ctx_hi = (unsigned short*)(ws);
  unsigned short* ctx_lo = (unsigned short*)(ws + 33554432);
  unsigned short* wih_hi = (unsigned short*)(ws + 67108864);
  unsigned short* wih_lo = (unsigned short*)(ws + 92274688);
  unsigned short* whh_hi = (unsigned short*)(ws + 117440512);
  unsigned short* whh_lo = (unsigned short*)(ws + 119013376);
  float*          ctxW   = (float*)(ws + 120586240);
  unsigned int*   hbuf   = (unsigned int*)(ws + 133169152);
  float*          kdot   = (float*)(ws + 133300224);
  float*          bdot   = (float*)(ws + 133308544);
  int*            syncb  = (int*)(ws + 133316864);

  k_prep<<<49152, 256, 0, stream>>>(wih, whh, ob, wih_hi, wih_lo, whh_hi, whh_lo,
                                    hbuf, kdot, bdot, syncb, out);
  k_conv<<<2048, 128, 0, stream>>>(x, cw, ctx_hi, ctx_lo);
  k_gemm<<<dim3(16, 12), 256, 0, stream>>>(ctx_hi, ctx_lo, wih_hi, wih_lo, ctxW);
  k_scan<<<NWG, 512, 0, stream>>>(ctxW, whh_hi, whh_lo, kw, bw, ow,
                                  hbuf, kdot, bdot, syncb, out);
}

// Round 3
// 1429.911 us; speedup vs baseline: 1.9232x; 1.9232x over previous
//
#include <hip/hip_runtime.h>

using f32x4  = __attribute__((ext_vector_type(4))) float;
using short8 = __attribute__((ext_vector_type(8))) short;
using u32x4  = __attribute__((ext_vector_type(4))) unsigned int;

#define DEV __device__ __forceinline__
#define MFMA16(a, b, c) __builtin_amdgcn_mfma_f32_16x16x32_bf16(a, b, c, 0, 0, 0)

// B=32, CIN=1, NBINS=128, NFRAMES=256, NFILT=64 -> Hc=64, Wc=128
// context: [2048][8192] (row m = b*64+l, col f = c*128+w)
// DDEC=512, G=1536, T=64, NCLS=17, NWG=32

DEV unsigned short f2bf(float f) {
  unsigned int u = __float_as_uint(f);
  unsigned int r = (u + 0x7fffu + ((u >> 16) & 1u)) >> 16;
  return (unsigned short)r;
}
DEV float bf2f(unsigned short s) { return __uint_as_float(((unsigned int)s) << 16); }
DEV float sigm(float x) { return 1.0f / (1.0f + expf(-x)); }

// ---------------- K1: prep (split weights, zero scan state) ---------------------
__global__ __launch_bounds__(256) void k_prep(
    const float* __restrict__ wih, const float* __restrict__ whh,
    unsigned short* __restrict__ wih_hi, unsigned short* __restrict__ wih_lo,
    unsigned short* __restrict__ whh_hi, unsigned short* __restrict__ whh_lo,
    unsigned int* __restrict__ hbuf, float* __restrict__ kpart,
    float* __restrict__ bpart, int* __restrict__ flags) {
  unsigned int i = blockIdx.x * 256u + threadIdx.x;
  if (i < 12582912u) {
    float w = wih[i];
    unsigned short h = f2bf(w);
    wih_hi[i] = h;
    wih_lo[i] = f2bf(w - bf2f(h));
  }
  if (i < 786432u) {
    float w = whh[i];
    unsigned short h = f2bf(w);
    whh_hi[i] = h;
    whh_lo[i] = f2bf(w - bf2f(h));
  }
  if (i < 32768u) hbuf[i] = 0u;
  if (i < 1024u) { kpart[i] = 0.f; bpart[i] = 0.f; }  // t=0 slice
  if (i < 32u) flags[i] = 0;
}

// ---------------- K2: conv 3x3 stride2 pad1 -> context (bf16 hi/lo) --------------
__global__ __launch_bounds__(128) void k_conv(
    const float* __restrict__ x, const float* __restrict__ cw,
    unsigned short* __restrict__ ctx_hi, unsigned short* __restrict__ ctx_lo) {
  __shared__ float w[576];
  int t = threadIdx.x;
  for (int i = t; i < 576; i += 128) w[i] = cw[i];
  int blk = blockIdx.x;  // b*64 + h
  int b = blk >> 6, h = blk & 63;
  const float* xb = x + (size_t)b * 32768;
  int wcol = t;
  float xv[3][3];
  int ih0 = 2 * h - 1, iw0 = 2 * wcol - 1;
#pragma unroll
  for (int kh = 0; kh < 3; kh++) {
    int ih = ih0 + kh;
#pragma unroll
    for (int kw = 0; kw < 3; kw++) {
      int iw = iw0 + kw;
      bool ok = (ih >= 0) && (ih < 128) && (iw >= 0) && (iw < 256);
      xv[kh][kw] = ok ? xb[ih * 256 + iw] : 0.f;
    }
  }
  __syncthreads();
  size_t base = (size_t)blk * 8192 + wcol;
  for (int c = 0; c < 64; c++) {
    const float* wc = &w[c * 9];
    float acc = 0.f;
#pragma unroll
    for (int kh = 0; kh < 3; kh++)
#pragma unroll
      for (int kw = 0; kw < 3; kw++) acc += xv[kh][kw] * wc[kh * 3 + kw];
    unsigned short hi = f2bf(acc);
    ctx_hi[base + c * 128] = hi;
    ctx_lo[base + c * 128] = f2bf(acc - bf2f(hi));
  }
}

// ---------------- K3: ctxW = context @ W_ih^T  (split-bf16, 3-term MFMA) ---------
__global__ __launch_bounds__(256) void k_gemm(
    const unsigned short* __restrict__ A_hi, const unsigned short* __restrict__ A_lo,
    const unsigned short* __restrict__ B_hi, const unsigned short* __restrict__ B_lo,
    float* __restrict__ ctxW) {
  __shared__ unsigned short Ah[128 * 32], Al[128 * 32], Bh[128 * 32], Bl[128 * 32];
  int tid = threadIdx.x;
  int m0 = blockIdx.x * 128, n0 = blockIdx.y * 128;
  int wave = tid >> 6, lane = tid & 63;
  int wm = wave >> 1, wn = wave & 1;
  const f32x4 zero4 = {0.f, 0.f, 0.f, 0.f};
  f32x4 acc[4][4];
  for (int mi = 0; mi < 4; mi++)
    for (int ni = 0; ni < 4; ni++) acc[mi][ni] = zero4;

  for (int k0 = 0; k0 < 8192; k0 += 32) {
    __syncthreads();
#pragma unroll
    for (int i = 0; i < 2; i++) {
      int c = tid + i * 256;
      int row = c >> 2, col = (c & 3) << 3;
      size_t ga = (size_t)(m0 + row) * 8192 + k0 + col;
      size_t gb = (size_t)(n0 + row) * 8192 + k0 + col;
      *(short8*)&Ah[row * 32 + col] = *(const short8*)&A_hi[ga];
      *(short8*)&Al[row * 32 + col] = *(const short8*)&A_lo[ga];
      *(short8*)&Bh[row * 32 + col] = *(const short8*)&B_hi[gb];
      *(short8*)&Bl[row * 32 + col] = *(const short8*)&B_lo[gb];
    }
    __syncthreads();
    int kc = (lane >> 4) * 8;
    short8 ah[4], al[4], bh[4], bl[4];
#pragma unroll
    for (int mi = 0; mi < 4; mi++) {
      int r = wm * 64 + mi * 16 + (lane & 15);
      ah[mi] = *(short8*)&Ah[r * 32 + kc];
      al[mi] = *(short8*)&Al[r * 32 + kc];
    }
#pragma unroll
    for (int ni = 0; ni < 4; ni++) {
      int r = wn * 64 + ni * 16 + (lane & 15);
      bh[ni] = *(short8*)&Bh[r * 32 + kc];
      bl[ni] = *(short8*)&Bl[r * 32 + kc];
    }
#pragma unroll
    for (int mi = 0; mi < 4; mi++)
#pragma unroll
      for (int ni = 0; ni < 4; ni++) {
        acc[mi][ni] = MFMA16(ah[mi], bh[ni], acc[mi][ni]);
        acc[mi][ni] = MFMA16(ah[mi], bl[ni], acc[mi][ni]);
        acc[mi][ni] = MFMA16(al[mi], bh[ni], acc[mi][ni]);
      }
  }
#pragma unroll
  for (int mi = 0; mi < 4; mi++)
#pragma unroll
    for (int ni = 0; ni < 4; ni++) {
      int n = n0 + wn * 64 + ni * 16 + (lane & 15);
#pragma unroll
      for (int r = 0; r < 4; r++) {
        int m = m0 + wm * 64 + mi * 16 + (lane >> 4) * 4 + r;
        // ctxW[l][b][n], m = b*64 + l
        ctxW[(size_t)((m & 63) * 32 + (m >> 6)) * 1536 + n] = acc[mi][ni][r];
      }
    }
}

// ---------------- K4: scan — 32 wgs (16 j-lanes each), flag sync, LDS-staged h ---
#define NWG 32

__global__ __launch_bounds__(512) void k_scan(
    const float* __restrict__ ctxW,
    const unsigned short* __restrict__ whh_hi, const unsigned short* __restrict__ whh_lo,
    const float* __restrict__ kw, const float* __restrict__ bw,
    const float* __restrict__ ow,
    unsigned int* __restrict__ hbuf, float* __restrict__ kpart,
    float* __restrict__ bpart, int* __restrict__ flags,
    float* __restrict__ pout, float* __restrict__ d_out) {
  __shared__ unsigned int h_lds[32][512];  // packed hi<<16|lo, 16B-XOR-swizzled
  __shared__ float ws_lds[32][64];
  __shared__ float gh_lds[32][48];
  __shared__ float hnew_lds[32][16];
  __shared__ float kappa_l[32], beta_l[32];

  const int g = blockIdx.x;
  const int tid = threadIdx.x;
  const int b = tid >> 4, jj = tid & 15;
  const int wave = tid >> 6, lane = tid & 63;
  const int j0 = g * 16;
  float h_prev = 0.f;

  if (tid < 32) kappa_l[tid] = 0.f;
  __syncthreads();

  for (int t = 0; t < 64; t++) {
    // ---- wait for all wgs to have published step t-1 ----
    if (t > 0) {
      if (tid < 32) {
        while (__hip_atomic_load(&flags[tid], __ATOMIC_ACQUIRE,
                                 __HIP_MEMORY_SCOPE_AGENT) < t)
          __builtin_amdgcn_s_sleep(1);
      }
      __syncthreads();
    }
    // ---- Phase A: stage h -> LDS (wide u64 atomic loads) + kappa/beta ----
    {
      const unsigned long long* hs =
          (const unsigned long long*)(hbuf + (t & 1) * 16384);
#pragma unroll
      for (int q = 0; q < 16; q++) {
        int m = tid + q * 512;  // u64 index, coalesced
        unsigned long long v = __hip_atomic_load(&hs[m], __ATOMIC_RELAXED,
                                                 __HIP_MEMORY_SCOPE_AGENT);
        int row = m >> 8;
        int ob = (m & 255) * 8;
        *(unsigned long long*)((char*)&h_lds[0][0] + row * 2048 +
                               (ob ^ ((row & 7) << 4))) = v;
      }
      if (tid < 32) {
        float ks = 0.f, bs = 0.f;
#pragma unroll 8
        for (int gg = 0; gg < 32; gg++) {
          ks += __hip_atomic_load(&kpart[(t * 32 + gg) * 32 + tid],
                                  __ATOMIC_RELAXED, __HIP_MEMORY_SCOPE_AGENT);
          bs += __hip_atomic_load(&bpart[(t * 32 + gg) * 32 + tid],
                                  __ATOMIC_RELAXED, __HIP_MEMORY_SCOPE_AGENT);
        }
        kappa_l[tid] += ks;
        beta_l[tid] = expf(bs);
      }
    }
    __syncthreads();
    // ---- Phase B: attention weights ----
#pragma unroll
    for (int p = 0; p < 4; p++) {
      int i = tid + p * 512;
      int bb = i >> 6, l = i & 63;
      float d = kappa_l[bb] - (float)l;
      float wv = expf(-beta_l[bb] * d * d);
      ws_lds[bb][l] = wv;
      if (bb == g) d_out[34816 + ((bb << 6) + t) * 64 + l] = wv;
    }
    __syncthreads();
    // ---- Phase C: gh MFMA (waves 0..5); waves 6-7 fall through to gx ----
    if (wave < 6) {
      int mt = wave & 1, nt = wave >> 1;
      int ar = mt * 16 + (lane & 15);                // batch row
      int n_g = nt * 512 + j0 + (lane & 15);         // global gate-row
      int sw = (ar & 7) << 4;
      const char* arow_p = (const char*)&h_lds[0][0] + ar * 2048;
      f32x4 acc = {0.f, 0.f, 0.f, 0.f};
      for (int ks = 0; ks < 16; ks++) {
        int ob = ks * 128 + (lane >> 4) * 32;
        u32x4 v1 = *(const u32x4*)(arow_p + (ob ^ sw));
        u32x4 v2 = *(const u32x4*)(arow_p + ((ob + 16) ^ sw));
        short8 ah, al;
#pragma unroll
        for (int q = 0; q < 4; q++) {
          ah[q] = (short)(v1[q] >> 16);
          al[q] = (short)(v1[q] & 0xffffu);
          ah[4 + q] = (short)(v2[q] >> 16);
          al[4 + q] = (short)(v2[q] & 0xffffu);
        }
        int kc = ks * 32 + (lane >> 4) * 8;
        short8 bh = *(const short8*)&whh_hi[(size_t)n_g * 512 + kc];
        short8 bl = *(const short8*)&whh_lo[(size_t)n_g * 512 + kc];
        acc = MFMA16(ah, bh, acc);
        acc = MFMA16(ah, bl, acc);
        acc = MFMA16(al, bh, acc);
      }
#pragma unroll
      for (int r = 0; r < 4; r++)
        gh_lds[mt * 16 + (lane >> 4) * 4 + r][nt * 16 + (lane & 15)] = acc[r];
    }
    // ---- Phase D: gx from ctxW (all threads; overlaps C for waves 6-7) ----
    float gx0 = 0.f, gx1 = 0.f, gx2 = 0.f;
    {
      const float* cbase = ctxW + (size_t)b * 1536 + j0 + jj;
#pragma unroll 8
      for (int l = 0; l < 64; l++) {
        float wv = ws_lds[b][l];
        const float* cp = cbase + (size_t)l * 49152;
        gx0 = fmaf(wv, cp[0], gx0);
        gx1 = fmaf(wv, cp[512], gx1);
        gx2 = fmaf(wv, cp[1024], gx2);
      }
    }
    __syncthreads();
    // ---- Phase E: gates + hidden update + publish partial dots ----
    {
      float rr = sigm(gx0 + gh_lds[b][jj]);
      float zz = sigm(gx1 + gh_lds[b][16 + jj]);
      float nn = tanhf(gx2 + rr * gh_lds[b][32 + jj]);
      float h = (1.f - zz) * nn + zz * h_prev;
      h_prev = h;
      hnew_lds[b][jj] = h;
      unsigned short hh = f2bf(h);
      unsigned short hl = f2bf(h - bf2f(hh));
      __hip_atomic_store(&hbuf[((t + 1) & 1) * 16384 + b * 512 + j0 + jj],
                         ((unsigned int)hh << 16) | (unsigned int)hl,
                         __ATOMIC_RELAXED, __HIP_MEMORY_SCOPE_AGENT);
      float kd = h * kw[j0 + jj];
      float bd = h * bw[j0 + jj];
#pragma unroll
      for (int m = 1; m < 16; m <<= 1) {
        kd += __shfl_xor(kd, m, 64);
        bd += __shfl_xor(bd, m, 64);
      }
      if (jj == 0) {
        __hip_atomic_store(&kpart[((t + 1) * 32 + g) * 32 + b], kd,
                           __ATOMIC_RELAXED, __HIP_MEMORY_SCOPE_AGENT);
        __hip_atomic_store(&bpart[((t + 1) * 32 + g) * 32 + b], bd,
                           __ATOMIC_RELAXED, __HIP_MEMORY_SCOPE_AGENT);
      }
    }
    __syncthreads();
    // ---- publish step-t completion (hbuf/kpart stores are barrier-ordered) ----
    if (tid == 0)
      __hip_atomic_store(&flags[g], t + 1, __ATOMIC_RELEASE,
                         __HIP_MEMORY_SCOPE_AGENT);
    // ---- Phase F: out-projection partials (strided: 544 items, 512 threads) ----
    for (int i = tid; i < 544; i += 512) {
      int bo = i / 17, k = i - bo * 17;
      const float* owr = ow + k * 512 + j0;
      float s = 0.f;
#pragma unroll
      for (int j = 0; j < 16; j++) s += hnew_lds[bo][j] * owr[j];
      pout[((t * 32 + g) * 32 + bo) * 17 + k] = s;
    }
  }
}

// ---------------- K5: reduce pout over wgs + bias -> d_out ----------------------
__global__ __launch_bounds__(256) void k_fin(
    const float* __restrict__ pout, const float* __restrict__ ob,
    float* __restrict__ d_out) {
  int i = blockIdx.x * 256 + threadIdx.x;
  if (i >= 34816) return;
  int k = i % 17;
  int bt = i / 17;
  int b = bt >> 6, t = bt & 63;
  float s = ob[k];
#pragma unroll 8
  for (int g = 0; g < 32; g++) s += pout[((t * 32 + g) * 32 + b) * 17 + k];
  d_out[i] = s;
}

// ---------------- launch ----------------
extern "C" void kernel_launch(void* const* d_in, const int* in_sizes, int n_in,
                              void* d_out, int out_size, void* d_ws, size_t ws_size,
                              hipStream_t stream) {
  (void)in_sizes; (void)n_in; (void)out_size; (void)ws_size;
  const float* x   = (const float*)d_in[0];
  const float* cw  = (const float*)d_in[2];
  const float* kw  = (const float*)d_in[3];
  const float* bw  = (const float*)d_in[4];
  const float* wih = (const float*)d_in[5];
  const float* whh = (const float*)d_in[6];
  const float* ow  = (const float*)d_in[7];
  const float* ob  = (const float*)d_in[8];
  float* out = (float*)d_out;
  char* ws = (char*)d_ws;

  unsigned short* ctx_hi = (unsigned short*)(ws);
  unsigned short* ctx_lo = (unsigned short*)(ws + 33554432);
  unsigned short* wih_hi = (unsigned short*)(ws + 67108864);
  unsigned short* wih_lo = (unsigned short*)(ws + 92274688);
  unsigned short* whh_hi = (unsigned short*)(ws + 117440512);
  unsigned short* whh_lo = (unsigned short*)(ws + 119013376);
  float*          ctxW   = (float*)(ws + 120586240);
  unsigned int*   hbuf   = (unsigned int*)(ws + 133169152);
  float*          kpart  = (float*)(ws + 133300224);  // [65][32][32]
  float*          bpart  = (float*)(ws + 133566464);  // [65][32][32]
  int*            flags  = (int*)(ws + 133832704);    // [32]
  float*          pout   = (float*)(ws);              // overlay ctx_hi (dead after k_gemm)

  k_prep<<<49152, 256, 0, stream>>>(wih, whh, wih_hi, wih_lo, whh_hi, whh_lo,
                                    hbuf, kpart, bpart, flags);
  k_conv<<<2048, 128, 0, stream>>>(x, cw, ctx_hi, ctx_lo);
  k_gemm<<<dim3(16, 12), 256, 0, stream>>>(ctx_hi, ctx_lo, wih_hi, wih_lo, ctxW);
  k_scan<<<NWG, 512, 0, stream>>>(ctxW, whh_hi, whh_lo, kw, bw, ow,
                                  hbuf, kpart, bpart, flags, pout, out);
  k_fin<<<136, 256, 0, stream>>>(pout, ob, out);
}